// Round 1
// baseline (253.105 us; speedup 1.0000x reference)
//
#include <hip/hip_runtime.h>
#include <math.h>

// RWKV-6 fused recurrent WKV, chunked-linear-scan formulation.
// B=4, T=2048, H=16, N=64, fp32 everywhere.
//
// Recurrence per (b,h):   S[i][j] <- d_t[i]*S[i][j] + k_t[i]*v_t[j]
//   o_t[j] = sum_i r_t[i]*(S_prev[i][j] + u[i]*k_t[i]*v_t[j])
// Linear in S => chunk the T axis:
//   K1: per chunk, local recurrence from zero state -> L_g[i][j], A_g[i]=prod d
//   K2: per (b,h,i,j), scan S0_{g+1} = A_g[i]*S0_g + L_g   (in-place: L becomes S0)
//   K3: per chunk, rerun recurrence initialized with S0_g -> outputs

namespace {
constexpr int B = 4, T = 2048, H = 16, N = 64;
constexpr int G = 32;            // chunks per (b,h)
constexpr int TC = T / G;        // 64 steps per chunk
constexpr int BH = B * H;        // 64 sequential chains

__device__ __forceinline__ float decay_of(float w) {
    // RWKV-6 parameterization: d = exp(-exp(w)) in (0,1)
    return expf(-expf(w));
}

// ---------------- K1: chunk-local recurrence from zero state ----------------
__global__ __launch_bounds__(64)
void k1_chunk_local(const float* __restrict__ kp, const float* __restrict__ vp,
                    const float* __restrict__ wp,
                    float* __restrict__ L, float* __restrict__ A)
{
    const int blk = blockIdx.x;          // bh*G + g
    const int g   = blk & (G - 1);
    const int bh  = blk / G;
    const int b   = bh / H;
    const int h   = bh - b * H;
    const int j   = threadIdx.x;         // value-column owned by this lane

    __shared__ float2 kd[2][N];          // {k_i, d_i} broadcast buffers (dbuf)

    float S[N];                          // column j of the state, in VGPRs
#pragma unroll
    for (int i = 0; i < N; ++i) S[i] = 0.f;

    float ad = 1.f;                      // running per-i decay product (i == j here)
    const int t0 = g * TC;
    for (int tt = 0; tt < TC; ++tt) {
        const int t    = t0 + tt;
        const int base = ((b * T + t) * H + h) * N + j;
        const float kj = kp[base];
        const float vj = vp[base];
        const float dj = decay_of(wp[base]);
        ad *= dj;
        const int par = tt & 1;
        kd[par][j] = make_float2(kj, dj);
        __syncthreads();
#pragma unroll
        for (int i = 0; i < N; ++i) {
            const float2 x = kd[par][i];             // ds_read_b64 broadcast
            S[i] = fmaf(x.y, S[i], x.x * vj);        // S = d_i*S + k_i*v_j
        }
    }

    const int lbase = (bh * G + g) * (N * N) + j;
#pragma unroll
    for (int i = 0; i < N; ++i) L[lbase + i * N] = S[i];   // coalesced over j
    A[(bh * G + g) * N + j] = ad;
}

// ---------------- K2: inter-chunk scan, in place (L -> S0) ------------------
__global__ __launch_bounds__(256)
void k2_scan(float* __restrict__ L, const float* __restrict__ A)
{
    const int tid = blockIdx.x * 256 + threadIdx.x;  // (bh, i, j), j fastest
    const int j  = tid & (N - 1);
    const int i  = (tid >> 6) & (N - 1);
    const int bh = tid >> 12;

    float S = 0.f;
    const int lstride = N * N;
    int lidx = bh * G * lstride + i * N + j;
    int aidx = bh * G * N + i;
    for (int g = 0; g < G; ++g) {
        const float l = L[lidx];
        const float a = A[aidx];
        L[lidx] = S;                 // overwrite with state at START of chunk g
        S = fmaf(a, S, l);
        lidx += lstride;
        aidx += N;
    }
}

// ---------------- K3: chunk recurrence with true init state -> outputs ------
// Also serves as the no-workspace sequential fallback (NG==1, S0==nullptr).
template<int STEPS, int NG>
__global__ __launch_bounds__(64)
void k3_chunk_out(const float* __restrict__ rp, const float* __restrict__ kp,
                  const float* __restrict__ vp, const float* __restrict__ wp,
                  const float* __restrict__ up, const float* __restrict__ S0,
                  float* __restrict__ out)
{
    const int blk = blockIdx.x;
    const int g   = blk & (NG - 1);
    const int bh  = blk / NG;
    const int b   = bh / H;
    const int h   = bh - b * H;
    const int j   = threadIdx.x;

    __shared__ float4 sh[2][N];          // {r_i, k_i, d_i, r_i*u_i}

    float S[N];
    if (S0 != nullptr) {
        const int lbase = (bh * NG + g) * (N * N) + j;
#pragma unroll
        for (int i = 0; i < N; ++i) S[i] = S0[lbase + i * N];
    } else {
#pragma unroll
        for (int i = 0; i < N; ++i) S[i] = 0.f;
    }

    const float uj = up[h * N + j];

    const int t0 = g * STEPS;
    for (int tt = 0; tt < STEPS; ++tt) {
        const int t    = t0 + tt;
        const int base = ((b * T + t) * H + h) * N + j;
        const float rj = rp[base];
        const float kj = kp[base];
        const float vj = vp[base];
        const float dj = decay_of(wp[base]);
        const int par = tt & 1;
        sh[par][j] = make_float4(rj, kj, dj, rj * uj);
        __syncthreads();

        // Split accumulators: break the 64-deep dependent FMA chain (4cyc dep lat).
        float o0 = 0.f, o1 = 0.f, o2 = 0.f, o3 = 0.f;
        float q0 = 0.f, q1 = 0.f;
#pragma unroll
        for (int i = 0; i < N; ++i) {
            const float4 x = sh[par][i];             // ds_read_b128 broadcast
            if ((i & 3) == 0)      o0 = fmaf(x.x, S[i], o0);
            else if ((i & 3) == 1) o1 = fmaf(x.x, S[i], o1);
            else if ((i & 3) == 2) o2 = fmaf(x.x, S[i], o2);
            else                   o3 = fmaf(x.x, S[i], o3);
            if (i & 1) q1 = fmaf(x.w, x.y, q1);
            else       q0 = fmaf(x.w, x.y, q0);
            S[i] = fmaf(x.z, S[i], x.y * vj);        // state update
        }
        const float o    = (o0 + o1) + (o2 + o3);
        const float sruk = q0 + q1;                  // sum_i r_i*u_i*k_i
        out[base] = fmaf(sruk, vj, o);
    }
}

} // anon namespace

extern "C" void kernel_launch(void* const* d_in, const int* in_sizes, int n_in,
                              void* d_out, int out_size, void* d_ws, size_t ws_size,
                              hipStream_t stream)
{
    const float* r = (const float*)d_in[0];
    const float* k = (const float*)d_in[1];
    const float* v = (const float*)d_in[2];
    const float* w = (const float*)d_in[3];
    const float* u = (const float*)d_in[4];
    float* out = (float*)d_out;

    const size_t l_elems = (size_t)BH * G * N * N;        // 8,388,608
    const size_t a_elems = (size_t)BH * G * N;            // 131,072
    const size_t ws_need = (l_elems + a_elems) * sizeof(float);  // ~32.5 MiB

    if (ws_size >= ws_need) {
        float* L = (float*)d_ws;
        float* A = L + l_elems;
        k1_chunk_local<<<BH * G, 64, 0, stream>>>(k, v, w, L, A);
        k2_scan<<<(BH * N * N) / 256, 256, 0, stream>>>(L, A);
        k3_chunk_out<TC, G><<<BH * G, 64, 0, stream>>>(r, k, v, w, u, L, out);
    } else {
        // No-workspace fallback: fully sequential per (b,h). Slow but correct.
        k3_chunk_out<T, 1><<<BH, 64, 0, stream>>>(r, k, v, w, u, nullptr, out);
    }
}

// Round 2
// 220.871 us; speedup vs baseline: 1.1459x; 1.1459x over previous
//
#include <hip/hip_runtime.h>
#include <math.h>

// RWKV-6 fused recurrent WKV, chunked-linear-scan formulation.
// B=4, T=2048, H=16, N=64, fp32.
//
// Per (b,h):  S[i][j] <- d_t[i]*S[i][j] + k_t[i]*v_t[j]
//             o_t[j]  = sum_i r_i*S_ij  +  v_j * sum_i(r_i*u_i*k_i)
// Linear in S => chunk T into G chunks:
//   K1: per chunk, recurrence from zero -> L_g[i][j], A_g[i] = prod d
//   K2: per (b,h,i,j): scan S0_{g+1} = A_g[i]*S0_g + L_g  (in place, L -> S0)
//   K3: per chunk, recurrence from S0_g -> outputs
// Blocks are single-wave (64 lanes, lane j owns state column j) -> no barriers
// needed: LDS ops are in-order within a wave and the compiler preserves
// may-alias ds_write->ds_read program order.

namespace {
constexpr int B = 4, T = 2048, H = 16, N = 64;
constexpr int BH = B * H;

__device__ __forceinline__ float decay_of(float w) {
    return expf(-expf(w));   // RWKV-6: d = exp(-exp(w)) in (0,1)
}

__device__ __forceinline__ float wave_sum64(float x) {
#pragma unroll
    for (int m = 1; m < 64; m <<= 1) x += __shfl_xor(x, m, 64);
    return x;
}

// ---------------- K1: chunk-local recurrence from zero state ----------------
template<int STEPS, int NG>
__global__ __launch_bounds__(64, 4)
void k1_chunk_local(const float* __restrict__ kp, const float* __restrict__ vp,
                    const float* __restrict__ wp,
                    float* __restrict__ L, float* __restrict__ A)
{
    const int blk = blockIdx.x;          // bh*NG + g
    const int g   = blk & (NG - 1);
    const int bh  = blk / NG;
    const int b   = bh / H;
    const int h   = bh - b * H;
    const int j   = threadIdx.x;

    __shared__ float2 kd[2][N];          // {k_i, d_i} broadcast (double buffer)

    float S[N];
#pragma unroll
    for (int i = 0; i < N; ++i) S[i] = 0.f;

    float ad = 1.f;                      // running decay product for i == j
    const int stride = H * N;
    int base = ((b * T + g * STEPS) * H + h) * N + j;

    float kj = kp[base], vj = vp[base], wj = wp[base];
    for (int tt = 0; tt < STEPS; ++tt) {
        const int nb = (tt + 1 < STEPS) ? base + stride : base;  // clamped prefetch
        const float kn = kp[nb], vn = vp[nb], wn = wp[nb];

        const float dj = decay_of(wj);
        ad *= dj;
        const int par = tt & 1;
        kd[par][j] = make_float2(kj, dj);
#pragma unroll
        for (int i = 0; i < N; ++i) {
            const float2 x = kd[par][i];             // broadcast ds_read_b64
            S[i] = fmaf(x.y, S[i], x.x * vj);
        }
        base = nb; kj = kn; vj = vn; wj = wn;
    }

    const int lbase = (bh * NG + g) * (N * N) + j;
#pragma unroll
    for (int i = 0; i < N; ++i) L[lbase + i * N] = S[i];   // coalesced over j
    A[(bh * NG + g) * N + j] = ad;
}

// ---------------- K2: inter-chunk scan, in place (L -> S0), float4 ----------
__global__ __launch_bounds__(256)
void k2_scan(float* __restrict__ L, const float* __restrict__ A, int NG)
{
    const int tid = blockIdx.x * 256 + threadIdx.x;   // over BH*N*N/4
    const int j4 = tid & (N / 4 - 1);
    const int i  = (tid >> 4) & (N - 1);
    const int bh = tid >> 10;

    float4* L4 = (float4*)L;
    const int lstride = N * N / 4;
    int lidx = bh * NG * lstride + i * (N / 4) + j4;
    int aidx = bh * NG * N + i;

    float4 S = make_float4(0.f, 0.f, 0.f, 0.f);
    for (int g = 0; g < NG; ++g) {
        const float4 l = L4[lidx];
        const float  a = A[aidx];
        L4[lidx] = S;                // state at START of chunk g
        S.x = fmaf(a, S.x, l.x);
        S.y = fmaf(a, S.y, l.y);
        S.z = fmaf(a, S.z, l.z);
        S.w = fmaf(a, S.w, l.w);
        lidx += lstride;
        aidx += N;
    }
}

// ---------------- K3: chunk recurrence with true init state -> outputs ------
template<int STEPS, int NG>
__global__ __launch_bounds__(64, 4)
void k3_chunk_out(const float* __restrict__ rp, const float* __restrict__ kp,
                  const float* __restrict__ vp, const float* __restrict__ wp,
                  const float* __restrict__ up, const float* __restrict__ S0,
                  float* __restrict__ out)
{
    const int blk = blockIdx.x;
    const int g   = blk & (NG - 1);
    const int bh  = blk / NG;
    const int b   = bh / H;
    const int h   = bh - b * H;
    const int j   = threadIdx.x;

    __shared__ float4 sh[2][N];          // {r_i, k_i, d_i, -}

    float S[N];
    if (S0 != nullptr) {
        const int lbase = (bh * NG + g) * (N * N) + j;
#pragma unroll
        for (int i = 0; i < N; ++i) S[i] = S0[lbase + i * N];
    } else {
#pragma unroll
        for (int i = 0; i < N; ++i) S[i] = 0.f;
    }

    const float uj = up[h * N + j];
    const int stride = H * N;
    int base = ((b * T + g * STEPS) * H + h) * N + j;

    float rj = rp[base], kj = kp[base], vj = vp[base], wj = wp[base];
    for (int tt = 0; tt < STEPS; ++tt) {
        const int nb = (tt + 1 < STEPS) ? base + stride : base;  // clamped prefetch
        const float rn = rp[nb], kn = kp[nb], vn = vp[nb], wn = wp[nb];

        const float dj = decay_of(wj);
        // sum_i r_i*u_i*k_i is lane-independent: one product + wave reduction
        const float sruk = wave_sum64(rj * uj * kj);

        const int par = tt & 1;
        sh[par][j] = make_float4(rj, kj, dj, 0.f);

        float o0 = 0.f, o1 = 0.f, o2 = 0.f, o3 = 0.f;
#pragma unroll
        for (int i = 0; i < N; i += 4) {
            const float4 x0 = sh[par][i];
            const float4 x1 = sh[par][i + 1];
            const float4 x2 = sh[par][i + 2];
            const float4 x3 = sh[par][i + 3];
            o0 = fmaf(x0.x, S[i],     o0); S[i]     = fmaf(x0.z, S[i],     x0.y * vj);
            o1 = fmaf(x1.x, S[i + 1], o1); S[i + 1] = fmaf(x1.z, S[i + 1], x1.y * vj);
            o2 = fmaf(x2.x, S[i + 2], o2); S[i + 2] = fmaf(x2.z, S[i + 2], x2.y * vj);
            o3 = fmaf(x3.x, S[i + 3], o3); S[i + 3] = fmaf(x3.z, S[i + 3], x3.y * vj);
        }
        out[base] = fmaf(sruk, vj, (o0 + o1) + (o2 + o3));

        base = nb; rj = rn; kj = kn; vj = vn; wj = wn;
    }
}

} // anon namespace

extern "C" void kernel_launch(void* const* d_in, const int* in_sizes, int n_in,
                              void* d_out, int out_size, void* d_ws, size_t ws_size,
                              hipStream_t stream)
{
    const float* r = (const float*)d_in[0];
    const float* k = (const float*)d_in[1];
    const float* v = (const float*)d_in[2];
    const float* w = (const float*)d_in[3];
    const float* u = (const float*)d_in[4];
    float* out = (float*)d_out;

    auto ws_need = [](int NG) {
        return ((size_t)BH * NG * N * N + (size_t)BH * NG * N) * sizeof(float);
    };

    if (ws_size >= ws_need(64)) {
        constexpr int NG = 64, TC = T / NG;
        float* L = (float*)d_ws;
        float* A = L + (size_t)BH * NG * N * N;
        k1_chunk_local<TC, NG><<<BH * NG, 64, 0, stream>>>(k, v, w, L, A);
        k2_scan<<<(BH * N * N / 4) / 256, 256, 0, stream>>>(L, A, NG);
        k3_chunk_out<TC, NG><<<BH * NG, 64, 0, stream>>>(r, k, v, w, u, L, out);
    } else if (ws_size >= ws_need(32)) {
        constexpr int NG = 32, TC = T / NG;
        float* L = (float*)d_ws;
        float* A = L + (size_t)BH * NG * N * N;
        k1_chunk_local<TC, NG><<<BH * NG, 64, 0, stream>>>(k, v, w, L, A);
        k2_scan<<<(BH * N * N / 4) / 256, 256, 0, stream>>>(L, A, NG);
        k3_chunk_out<TC, NG><<<BH * NG, 64, 0, stream>>>(r, k, v, w, u, L, out);
    } else {
        // No-workspace fallback: fully sequential per (b,h). Slow but correct.
        k3_chunk_out<T, 1><<<BH, 64, 0, stream>>>(r, k, v, w, u, nullptr, out);
    }
}